// Round 11
// baseline (396.033 us; speedup 1.0000x reference)
//
#include <hip/hip_runtime.h>
#include <math.h>

constexpr int B = 2, A = 900, ED = 256, NG = 8, NCAM = 6, NL = 4, NP = 7;
constexpr int NJ = NG * NCAM * NL * NP;   // 1344
constexpr int NBA = B * A;                // 1800
constexpr int NE = NCAM * NL * NP;        // 168 point-level entries
constexpr int SPLIT = 2;                  // entry-loop split across blocks
constexpr int EHALF = NE / SPLIT;         // 84

// merged prep: 1575 FC blocks first, then 2-tile transpose blocks
constexpr int NFCB  = 225 * 7;            // 1575 FC blocks (8 anchors x 192 j)
constexpr int TPB   = 935;                // 704(l0)+176(l1)+44(l2)+11(l3)
constexpr int NTRB  = TPB * B * NCAM;     // 11220 tiles
constexpr int NTRB2 = NTRB / 2;           // 5610 blocks (2 tiles each)

// native clang vector for nontemporal builtins (HIP float4 is rejected)
typedef float nfloat4 __attribute__((ext_vector_type(4)));

__constant__ float FIXS[NP][3] = {
  {0.f,0.f,0.f},{0.45f,0.f,0.f},{-0.45f,0.f,0.f},
  {0.f,0.45f,0.f},{0.f,-0.45f,0.f},{0.f,0.f,0.45f},{0.f,0.f,-0.45f}};

__constant__ int cH[NL]  = {64,32,16,8};
__constant__ int cW[NL]  = {176,88,44,22};
__constant__ int cHW[NL] = {11264,2816,704,176};
// float offsets of levels 0..3 inside tfeat (ALL levels channel-last)
__constant__ long long cLOFF[NL] = {0LL, 34603008LL, 43253760LL, 45416448LL};

struct TI { const float* inb; float* outb; int px0, ch0, HW; bool big; };

__device__ __forceinline__ TI tile_info(int tt,
    const float* f0, const float* f1, const float* f2, const float* f3,
    float* tfeat)
{
  TI ti;
  const int bc = tt / TPB;
  const int bx = tt % TPB;
  int lvl;
  const float* src;
  if (bx < 704)      { lvl = 0; src = f0; ti.px0 = (bx >> 2) * 64;         ti.ch0 = (bx & 3) * 64; }
  else if (bx < 880) { lvl = 1; src = f1; ti.px0 = ((bx - 704) >> 2) * 64; ti.ch0 = ((bx - 704) & 3) * 64; }
  else if (bx < 924) { lvl = 2; src = f2; ti.px0 = ((bx - 880) >> 2) * 64; ti.ch0 = ((bx - 880) & 3) * 64; }
  else               { lvl = 3; src = f3; ti.px0 = (bx - 924) * 16;        ti.ch0 = 0; }
  ti.HW  = cHW[lvl];
  ti.big = (lvl < 3);
  ti.inb  = src + (size_t)bc * ED * ti.HW;
  ti.outb = tfeat + cLOFF[lvl] + (size_t)bc * ti.HW * ED;
  return ti;
}

__device__ __forceinline__ void tile_load(const TI& ti, int t, nfloat4 r[4]) {
  if (ti.big) {
    const int pxl = t & 15, cr = t >> 4;
#pragma unroll
    for (int i = 0; i < 4; ++i)
      r[i] = *reinterpret_cast<const nfloat4*>(
          ti.inb + (size_t)(ti.ch0 + cr + 16*i)*ti.HW + ti.px0 + 4*pxl);
  } else {
    const int pxl = t & 3, cr = t >> 2;
#pragma unroll
    for (int i = 0; i < 4; ++i)
      r[i] = *reinterpret_cast<const nfloat4*>(
          ti.inb + (size_t)(cr + 64*i)*ti.HW + ti.px0 + 4*pxl);
  }
}

__device__ __forceinline__ void tile_lds(float* buf, const TI& ti, int t,
                                         const nfloat4 r[4]) {
  if (ti.big) {
    const int pxl = t & 15, cr = t >> 4;
#pragma unroll
    for (int i = 0; i < 4; ++i) {
      const int ch = cr + 16*i;
      buf[(4*pxl+0)*65 + ch] = r[i].x;
      buf[(4*pxl+1)*65 + ch] = r[i].y;
      buf[(4*pxl+2)*65 + ch] = r[i].z;
      buf[(4*pxl+3)*65 + ch] = r[i].w;
    }
  } else {
    const int pxl = t & 3, cr = t >> 2;
#pragma unroll
    for (int i = 0; i < 4; ++i) {
      const int ch = cr + 64*i;
      buf[(4*pxl+0)*257 + ch] = r[i].x;
      buf[(4*pxl+1)*257 + ch] = r[i].y;
      buf[(4*pxl+2)*257 + ch] = r[i].z;
      buf[(4*pxl+3)*257 + ch] = r[i].w;
    }
  }
}

__device__ __forceinline__ void tile_store(const float* buf, const TI& ti, int t) {
  if (ti.big) {
    const int chl = t & 15, pw = t >> 4;
#pragma unroll
    for (int i = 0; i < 4; ++i) {
      const int px = pw + 16*i;
      nfloat4 v;
      v.x = buf[px*65 + 4*chl + 0];
      v.y = buf[px*65 + 4*chl + 1];
      v.z = buf[px*65 + 4*chl + 2];
      v.w = buf[px*65 + 4*chl + 3];
      __builtin_nontemporal_store(v, reinterpret_cast<nfloat4*>(
          ti.outb + (size_t)(ti.px0 + px)*ED + ti.ch0 + 4*chl));
    }
  } else {
    const int chl = t & 63, pw = t >> 6;
#pragma unroll
    for (int i = 0; i < 4; ++i) {
      const int px = pw + 4*i;
      nfloat4 v;
      v.x = buf[px*257 + 4*chl + 0];
      v.y = buf[px*257 + 4*chl + 1];
      v.z = buf[px*257 + 4*chl + 2];
      v.w = buf[px*257 + 4*chl + 3];
      __builtin_nontemporal_store(v, reinterpret_cast<nfloat4*>(
          ti.outb + (size_t)(ti.px0 + px)*ED + 4*chl));
    }
  }
}

// ---- merged: {FC role, blocks [0,NFCB)} + {2-tile pipelined transpose} ----
__global__ __launch_bounds__(256) void k_prep(
    const float* __restrict__ f0, const float* __restrict__ f1,
    const float* __restrict__ f2, const float* __restrict__ f3,
    const float* __restrict__ inst, const float* __restrict__ emb,
    const float* __restrict__ w_fc, const float* __restrict__ b_fc,
    float* __restrict__ tfeat, float* __restrict__ wraw)
{
  __shared__ float smem[8320];      // 33.3 KB -> 4 blocks/CU
  const int bid = blockIdx.x;
  const int t   = threadIdx.x;

  if (bid < NFCB) {
    // ---------------- FC: wraw[a][j] = (inst+emb)[a] . w_fc[j] + b_fc ------
    float* fsh = smem;              // [8][256] features
    float* wts = smem + 2048;       // [32][193] staged w_fc^T chunk
    const int a0 = (bid / 7) * 8;
    const int j0 = (bid % 7) * 192;

    for (int i = t; i < 8 * ED; i += 256) {
      const int a = i >> 8, k = i & 255;
      const size_t idx = (size_t)(a0 + a) * ED + k;
      fsh[i] = inst[idx] + emb[idx];
    }

    float acc[8] = {0.f,0.f,0.f,0.f,0.f,0.f,0.f,0.f};
    for (int kc = 0; kc < 8; ++kc) {         // 8 chunks of 32 k
      __syncthreads();                        // fsh ready / wts reusable
      for (int idx = t; idx < 1536; idx += 256) {
        const int row = idx >> 3, q = idx & 7;
        const float4 v = *(const float4*)&w_fc[(size_t)(j0 + row)*ED + kc*32 + 4*q];
        wts[(4*q+0)*193 + row] = v.x;
        wts[(4*q+1)*193 + row] = v.y;
        wts[(4*q+2)*193 + row] = v.z;
        wts[(4*q+3)*193 + row] = v.w;
      }
      __syncthreads();
      if (t < 192) {
#pragma unroll
        for (int k = 0; k < 32; k += 4) {
          const float w0 = wts[(k+0)*193 + t];
          const float w1 = wts[(k+1)*193 + t];
          const float w2 = wts[(k+2)*193 + t];
          const float w3 = wts[(k+3)*193 + t];
          const int kb = kc * 32 + k;
#pragma unroll
          for (int a = 0; a < 8; ++a)
            acc[a] += w0*fsh[a*ED + kb]   + w1*fsh[a*ED + kb+1]
                    + w2*fsh[a*ED + kb+2] + w3*fsh[a*ED + kb+3];
        }
      }
    }
    if (t < 192) {
      const int j = j0 + t;
      const float bj = b_fc[j];
#pragma unroll
      for (int a = 0; a < 8; ++a)
        wraw[(size_t)(a0+a)*NJ + j] = acc[a] + bj;
    }
    return;
  }

  // ------- channel-last transpose: 2 tiles per block, double-buffered -----
  const int fb = bid - NFCB;
  const TI Ati = tile_info(2*fb + 0, f0, f1, f2, f3, tfeat);
  const TI Bti = tile_info(2*fb + 1, f0, f1, f2, f3, tfeat);
  float* bufA = smem;
  float* bufB = smem + 4160;

  nfloat4 ra[4], rb[4];
  tile_load(Ati, t, ra);
  tile_lds(bufA, Ati, t, ra);
  __syncthreads();
  tile_load(Bti, t, rb);          // issue B loads (in flight during A store)
  tile_store(bufA, Ati, t);       // LDS reads + NT global stores of A
  tile_lds(bufB, Bti, t, rb);     // waits on B loads
  __syncthreads();
  tile_store(bufB, Bti, t);
}

// ------- fused: softmax + projection + branchless compacted gather ----
// grid (NBA, SPLIT); CL=true: ALL levels channel-last from tfeat (coalesced
// 1KB taps). CL=false fallback: direct channel-first reads.
template<bool CL>
__global__ __launch_bounds__(256) void k_sample_h(
    const float* __restrict__ anchor, const float* __restrict__ proj,
    const float* __restrict__ wh, const float* __restrict__ wraw,
    const float* __restrict__ tfeat,
    const float* __restrict__ f0, const float* __restrict__ f1,
    const float* __restrict__ f2, const float* __restrict__ f3,
    float* __restrict__ fused)
{
  __shared__ float wsh[NJ];              // [g][e] layout (conflict-free)
  __shared__ float gridsh[NCAM][NP][2];
  __shared__ const float* cptr[EHALF][4]; // 4 pre-clamped tap pointers (ch 0)
  __shared__ float4 cwt[EHALF];           // validity-masked bilinear weights
  __shared__ int2   cmeta[EHALF];         // x=chstep, y=entry idx
  __shared__ int wcnt[4];

  const int ba   = blockIdx.x;
  const int half = blockIdx.y;
  const int b    = ba / A;
  const int t    = threadIdx.x;

  for (int j = t; j < NJ; j += 256)
    wsh[(j & 7) * NE + (j >> 3)] = wraw[(size_t)ba*NJ + j];

  if (t < NCAM*NP) {
    const int c = t / NP, p = t % NP;
    const float* an = anchor + (size_t)ba * 8;
    const float sx = expf(an[3]), sy = expf(an[4]), sz = expf(an[5]);
    const float sn = an[6], cs = an[7];
    const float kx = FIXS[p][0]*sx, ky = FIXS[p][1]*sy, kz = FIXS[p][2]*sz;
    const float px = cs*kx - sn*ky + an[0];
    const float py = sn*kx + cs*ky + an[1];
    const float pz = kz + an[2];
    const float* P = proj + ((size_t)(b*NCAM + c))*16;
    const float X = P[0]*px + P[1]*py + P[2]*pz  + P[3];
    const float Y = P[4]*px + P[5]*py + P[6]*pz  + P[7];
    const float Z = P[8]*px + P[9]*py + P[10]*pz + P[11];
    const float zc  = fmaxf(Z, 1e-5f);
    const float whx = fmaxf(wh[(b*NCAM+c)*2+0], 1e-5f);
    const float why = fmaxf(wh[(b*NCAM+c)*2+1], 1e-5f);
    gridsh[c][p][0] = (X/zc/whx)*2.f - 1.f;
    gridsh[c][p][1] = (Y/zc/why)*2.f - 1.f;
  }
  __syncthreads();

  // entries for this block: e = half*EHALF + (t if t < EHALF)
  bool valid = false;
  int chstep = 0;
  float4 w4 = make_float4(0.f,0.f,0.f,0.f);
  const float *p00=nullptr, *p10=nullptr, *p01=nullptr, *p11=nullptr;
  const int e = half * EHALF + t;
  if (t < EHALF) {
    const int c = e / (NL*NP); const int r = e % (NL*NP);
    const int l = r / NP, p = r % NP;
    const int Wl = cW[l], Hl = cH[l], HWl = cHW[l];
    const float gx = (gridsh[c][p][0] + 1.f) * (Wl * 0.5f) - 0.5f;
    const float gy = (gridsh[c][p][1] + 1.f) * (Hl * 0.5f) - 0.5f;
    const float x0f = floorf(gx), y0f = floorf(gy);
    const bool vx0 = (x0f >=  0.f) & (x0f <= (float)(Wl-1));
    const bool vx1 = (x0f >= -1.f) & (x0f <= (float)(Wl-2));
    const bool vy0 = (y0f >=  0.f) & (y0f <= (float)(Hl-1));
    const bool vy1 = (y0f >= -1.f) & (y0f <= (float)(Hl-2));
    if (vx0|vx1|vy0|vy1) {
      const float wx1 = gx - x0f, wy1 = gy - y0f;
      // clamp both tap coords into the image; invalid taps get weight 0
      const int x0 = (int)fmaxf(fminf(x0f,        (float)(Wl-1)), 0.f);
      const int x1 = (int)fmaxf(fminf(x0f + 1.f,  (float)(Wl-1)), 0.f);
      const int y0 = (int)fmaxf(fminf(y0f,        (float)(Hl-1)), 0.f);
      const int y1 = (int)fmaxf(fminf(y0f + 1.f,  (float)(Hl-1)), 0.f);
      w4 = make_float4((1.f-wx1)*(1.f-wy1)*(vx0&&vy0),
                       wx1*(1.f-wy1)*(vx1&&vy0),
                       (1.f-wx1)*wy1*(vx0&&vy1),
                       wx1*wy1*(vx1&&vy1));
      if (w4.x != 0.f || w4.y != 0.f || w4.z != 0.f || w4.w != 0.f) {
        const float* base;
        int estep;  // element stride for one pixel step
        if (CL) {
          base = tfeat + cLOFF[l] + (size_t)(b*NCAM + c) * HWl * ED;
          estep = ED; chstep = 1;
        } else {
          const float* fp = (l==0)?f0:(l==1)?f1:(l==2)?f2:f3;
          base = fp + (size_t)(b*NCAM + c) * ED * HWl;
          estep = 1; chstep = HWl;
        }
        p00 = base + (size_t)(y0*Wl + x0) * estep;
        p10 = base + (size_t)(y0*Wl + x1) * estep;
        p01 = base + (size_t)(y1*Wl + x0) * estep;
        p11 = base + (size_t)(y1*Wl + x1) * estep;
        valid = true;
      }
    }
  }

  const unsigned long long mask = __ballot(valid);
  const int lane = t & 63, wv = t >> 6;
  if (lane == 0) wcnt[wv] = __popcll(mask);
  __syncthreads();
  int off = 0, nv = 0;
#pragma unroll
  for (int i = 0; i < 4; ++i) { if (i < wv) off += wcnt[i]; nv += wcnt[i]; }
  if (valid) {
    const int pos = off + __popcll(mask & ((1ull << lane) - 1ull));
    cptr[pos][0] = p00; cptr[pos][1] = p10; cptr[pos][2] = p01; cptr[pos][3] = p11;
    cwt[pos]   = w4;
    cmeta[pos] = make_int2(chstep, e);
  }

  // group softmax over ALL entries (needed for correct normalization)
  {
    const int g = t >> 5, ln = t & 31;
    float* wg = wsh + g * NE;
    float m = -3.4e38f;
    for (int i = ln; i < NE; i += 32) m = fmaxf(m, wg[i]);
#pragma unroll
    for (int mk = 16; mk >= 1; mk >>= 1) m = fmaxf(m, __shfl_xor(m, mk));
    float s = 0.f;
    for (int i = ln; i < NE; i += 32) {
      const float ev = expf(wg[i] - m);
      wg[i] = ev;
      s += ev;
    }
#pragma unroll
    for (int mk = 16; mk >= 1; mk >>= 1) s += __shfl_xor(s, mk);
    const float inv = 1.f / s;
    for (int i = ln; i < NE; i += 32) wg[i] *= inv;
  }
  __syncthreads();

  float acc = 0.f;
  const int g = t >> 5;
#pragma unroll 4
  for (int i = 0; i < nv; ++i) {
    const int2 m = cmeta[i];
    const size_t toff = (size_t)t * m.x;
    const float4 w = cwt[i];
    const float aw = wsh[g*NE + m.y];
    const float v00 = cptr[i][0][toff];
    const float v10 = cptr[i][1][toff];
    const float v01 = cptr[i][2][toff];
    const float v11 = cptr[i][3][toff];
    acc += aw * (w.x*v00 + w.y*v10 + w.z*v01 + w.w*v11);
  }
  fused[((size_t)half * NBA + ba) * ED + t] = acc;
}

// ---------------- out = (fused0+fused1) @ w_out^T + b_out ----------------
__global__ __launch_bounds__(256) void k_out(const float* __restrict__ fused,
    const float* __restrict__ w_out, const float* __restrict__ b_out,
    float* __restrict__ out)
{
  __shared__ float fsh[8][ED];
  const int a0 = blockIdx.x * 8;
  const int t = threadIdx.x;
#pragma unroll
  for (int k = 0; k < 8; ++k)
    fsh[k][t] = fused[(size_t)(a0+k)*ED + t]
              + fused[(size_t)NBA*ED + (size_t)(a0+k)*ED + t];
  __syncthreads();
  float acc[8] = {0.f,0.f,0.f,0.f,0.f,0.f,0.f,0.f};
  for (int i = 0; i < ED; i += 4) {
    const float4 w4 = *(const float4*)&w_out[(size_t)t*ED + i];
#pragma unroll
    for (int k = 0; k < 8; ++k) {
      const float4 fv = *(const float4*)&fsh[k][i];
      acc[k] += w4.x*fv.x + w4.y*fv.y + w4.z*fv.z + w4.w*fv.w;
    }
  }
  const float bo = b_out[t];
#pragma unroll
  for (int k = 0; k < 8; ++k) out[(size_t)(a0+k)*ED + t] = acc[k] + bo;
}

extern "C" void kernel_launch(void* const* d_in, const int* in_sizes, int n_in,
                              void* d_out, int out_size, void* d_ws, size_t ws_size,
                              hipStream_t stream) {
  const float* inst   = (const float*)d_in[0];
  const float* anchor = (const float*)d_in[1];
  const float* emb    = (const float*)d_in[2];
  const float* f0 = (const float*)d_in[3];
  const float* f1 = (const float*)d_in[4];
  const float* f2 = (const float*)d_in[5];
  const float* f3 = (const float*)d_in[6];
  const float* proj  = (const float*)d_in[7];
  const float* wh    = (const float*)d_in[8];
  const float* w_fc  = (const float*)d_in[9];
  const float* b_fc  = (const float*)d_in[10];
  const float* w_out = (const float*)d_in[11];
  const float* b_out = (const float*)d_in[12];
  float* out = (float*)d_out;
  float* ws  = (float*)d_ws;

  const size_t TFEAT = 45957120ULL;   // ALL levels channel-last, floats
  const size_t WRAW  = (size_t)NBA * NJ;
  const size_t FUSED = (size_t)SPLIT * NBA * ED;
  const bool tr = ws_size >= (TFEAT + WRAW + FUSED) * sizeof(float);

  float* tfeat  = ws;
  float* wraw   = tr ? (ws + TFEAT) : ws;
  float* fusedp = wraw + WRAW;

  // merged: FC (1575 blocks, first) + 2-tile pipelined transpose (5610)
  k_prep<<<NFCB + (tr ? NTRB2 : 0), 256, 0, stream>>>(f0, f1, f2, f3,
      inst, emb, w_fc, b_fc, tfeat, wraw);

  if (tr)
    k_sample_h<true><<<dim3(NBA, SPLIT), 256, 0, stream>>>(anchor, proj, wh,
        wraw, tfeat, f0, f1, f2, f3, fusedp);
  else
    k_sample_h<false><<<dim3(NBA, SPLIT), 256, 0, stream>>>(anchor, proj, wh,
        wraw, tfeat, f0, f1, f2, f3, fusedp);

  k_out<<<NBA / 8, 256, 0, stream>>>(fusedp, w_out, b_out, out);
}

// Round 12
// 344.157 us; speedup vs baseline: 1.1507x; 1.1507x over previous
//
#include <hip/hip_runtime.h>
#include <math.h>

constexpr int B = 2, A = 900, ED = 256, NG = 8, NCAM = 6, NL = 4, NP = 7;
constexpr int NJ = NG * NCAM * NL * NP;   // 1344
constexpr int NBA = B * A;                // 1800
constexpr int NE = NCAM * NL * NP;        // 168 point-level entries
constexpr int SPLIT = 2;                  // entry-loop split across blocks
constexpr int EHALF = NE / SPLIT;         // 84

// merged prep: 1575 FC blocks first, then 2-tile transpose blocks
constexpr int NFCB  = 225 * 7;            // 1575 FC blocks (8 anchors x 192 j)
constexpr int TPB   = 935;                // 704(l0)+176(l1)+44(l2)+11(l3)
constexpr int NTRB  = TPB * B * NCAM;     // 11220 tiles
constexpr int NTRB2 = NTRB / 2;           // 5610 blocks (2 tiles each)

// native clang vector for nontemporal builtins (HIP float4 is rejected)
typedef float nfloat4 __attribute__((ext_vector_type(4)));

__constant__ float FIXS[NP][3] = {
  {0.f,0.f,0.f},{0.45f,0.f,0.f},{-0.45f,0.f,0.f},
  {0.f,0.45f,0.f},{0.f,-0.45f,0.f},{0.f,0.f,0.45f},{0.f,0.f,-0.45f}};

__constant__ int cH[NL]  = {64,32,16,8};
__constant__ int cW[NL]  = {176,88,44,22};
__constant__ int cHW[NL] = {11264,2816,704,176};
// float offsets of levels 0..3 inside tfeat (ALL levels channel-last)
__constant__ long long cLOFF[NL] = {0LL, 34603008LL, 43253760LL, 45416448LL};

struct TI { const float* inb; float* outb; int px0, ch0, HW; bool big; };

__device__ __forceinline__ TI tile_info(int tt,
    const float* f0, const float* f1, const float* f2, const float* f3,
    float* tfeat)
{
  TI ti;
  const int bc = tt / TPB;
  const int bx = tt % TPB;
  int lvl;
  const float* src;
  if (bx < 704)      { lvl = 0; src = f0; ti.px0 = (bx >> 2) * 64;         ti.ch0 = (bx & 3) * 64; }
  else if (bx < 880) { lvl = 1; src = f1; ti.px0 = ((bx - 704) >> 2) * 64; ti.ch0 = ((bx - 704) & 3) * 64; }
  else if (bx < 924) { lvl = 2; src = f2; ti.px0 = ((bx - 880) >> 2) * 64; ti.ch0 = ((bx - 880) & 3) * 64; }
  else               { lvl = 3; src = f3; ti.px0 = (bx - 924) * 16;        ti.ch0 = 0; }
  ti.HW  = cHW[lvl];
  ti.big = (lvl < 3);
  ti.inb  = src + (size_t)bc * ED * ti.HW;
  ti.outb = tfeat + cLOFF[lvl] + (size_t)bc * ti.HW * ED;
  return ti;
}

__device__ __forceinline__ void tile_load(const TI& ti, int t, nfloat4 r[4]) {
  if (ti.big) {
    const int pxl = t & 15, cr = t >> 4;
#pragma unroll
    for (int i = 0; i < 4; ++i)
      r[i] = *reinterpret_cast<const nfloat4*>(
          ti.inb + (size_t)(ti.ch0 + cr + 16*i)*ti.HW + ti.px0 + 4*pxl);
  } else {
    const int pxl = t & 3, cr = t >> 2;
#pragma unroll
    for (int i = 0; i < 4; ++i)
      r[i] = *reinterpret_cast<const nfloat4*>(
          ti.inb + (size_t)(cr + 64*i)*ti.HW + ti.px0 + 4*pxl);
  }
}

__device__ __forceinline__ void tile_lds(float* buf, const TI& ti, int t,
                                         const nfloat4 r[4]) {
  if (ti.big) {
    const int pxl = t & 15, cr = t >> 4;
#pragma unroll
    for (int i = 0; i < 4; ++i) {
      const int ch = cr + 16*i;
      buf[(4*pxl+0)*65 + ch] = r[i].x;
      buf[(4*pxl+1)*65 + ch] = r[i].y;
      buf[(4*pxl+2)*65 + ch] = r[i].z;
      buf[(4*pxl+3)*65 + ch] = r[i].w;
    }
  } else {
    const int pxl = t & 3, cr = t >> 2;
#pragma unroll
    for (int i = 0; i < 4; ++i) {
      const int ch = cr + 64*i;
      buf[(4*pxl+0)*257 + ch] = r[i].x;
      buf[(4*pxl+1)*257 + ch] = r[i].y;
      buf[(4*pxl+2)*257 + ch] = r[i].z;
      buf[(4*pxl+3)*257 + ch] = r[i].w;
    }
  }
}

__device__ __forceinline__ void tile_store(const float* buf, const TI& ti, int t) {
  if (ti.big) {
    const int chl = t & 15, pw = t >> 4;
#pragma unroll
    for (int i = 0; i < 4; ++i) {
      const int px = pw + 16*i;
      nfloat4 v;
      v.x = buf[px*65 + 4*chl + 0];
      v.y = buf[px*65 + 4*chl + 1];
      v.z = buf[px*65 + 4*chl + 2];
      v.w = buf[px*65 + 4*chl + 3];
      __builtin_nontemporal_store(v, reinterpret_cast<nfloat4*>(
          ti.outb + (size_t)(ti.px0 + px)*ED + ti.ch0 + 4*chl));
    }
  } else {
    const int chl = t & 63, pw = t >> 6;
#pragma unroll
    for (int i = 0; i < 4; ++i) {
      const int px = pw + 4*i;
      nfloat4 v;
      v.x = buf[px*257 + 4*chl + 0];
      v.y = buf[px*257 + 4*chl + 1];
      v.z = buf[px*257 + 4*chl + 2];
      v.w = buf[px*257 + 4*chl + 3];
      __builtin_nontemporal_store(v, reinterpret_cast<nfloat4*>(
          ti.outb + (size_t)(ti.px0 + px)*ED + 4*chl));
    }
  }
}

// ---- merged: {FC role} + {2-tile single-buffer register-prefetch transpose}
// LDS stays 16.6 KB -> 8 blocks/CU (the TLP that r11 lost); tile B is
// prefetched into regs while tile A stores, so loads stay in flight.
__global__ __launch_bounds__(256) void k_prep(
    const float* __restrict__ f0, const float* __restrict__ f1,
    const float* __restrict__ f2, const float* __restrict__ f3,
    const float* __restrict__ inst, const float* __restrict__ emb,
    const float* __restrict__ w_fc, const float* __restrict__ b_fc,
    float* __restrict__ tfeat, float* __restrict__ wraw)
{
  __shared__ float smem[4160];      // 16.6 KB -> 8 blocks/CU
  const int bid = blockIdx.x;
  const int t   = threadIdx.x;

  if (bid < NFCB) {
    // ---------------- FC: wraw[a][j] = (inst+emb)[a] . w_fc[j] + b_fc ------
    float* fsh = smem;              // [8][256] features
    float* wts = smem + 2048;       // [8][193] staged w_fc^T chunk
    const int a0 = (bid / 7) * 8;
    const int j0 = (bid % 7) * 192;

    for (int i = t; i < 8 * ED; i += 256) {
      const int a = i >> 8, k = i & 255;
      const size_t idx = (size_t)(a0 + a) * ED + k;
      fsh[i] = inst[idx] + emb[idx];
    }

    float acc[8] = {0.f,0.f,0.f,0.f,0.f,0.f,0.f,0.f};
    for (int kc = 0; kc < 32; ++kc) {        // 32 chunks of 8 k
      __syncthreads();                        // fsh ready / wts reusable
      for (int idx = t; idx < 384; idx += 256) {
        const int row = idx >> 1, q = idx & 1;
        const float4 v = *(const float4*)&w_fc[(size_t)(j0 + row)*ED + kc*8 + 4*q];
        wts[(4*q+0)*193 + row] = v.x;
        wts[(4*q+1)*193 + row] = v.y;
        wts[(4*q+2)*193 + row] = v.z;
        wts[(4*q+3)*193 + row] = v.w;
      }
      __syncthreads();
      if (t < 192) {
        const int kb = kc * 8;
#pragma unroll
        for (int k = 0; k < 8; k += 4) {
          const float w0 = wts[(k+0)*193 + t];
          const float w1 = wts[(k+1)*193 + t];
          const float w2 = wts[(k+2)*193 + t];
          const float w3 = wts[(k+3)*193 + t];
#pragma unroll
          for (int a = 0; a < 8; ++a)
            acc[a] += w0*fsh[a*ED + kb+k]   + w1*fsh[a*ED + kb+k+1]
                    + w2*fsh[a*ED + kb+k+2] + w3*fsh[a*ED + kb+k+3];
        }
      }
    }
    if (t < 192) {
      const int j = j0 + t;
      const float bj = b_fc[j];
#pragma unroll
      for (int a = 0; a < 8; ++a)
        wraw[(size_t)(a0+a)*NJ + j] = acc[a] + bj;
    }
    return;
  }

  // -- transpose: 2 tiles/block, single LDS buffer, register prefetch ------
  const int fb = bid - NFCB;
  const TI Ati = tile_info(2*fb + 0, f0, f1, f2, f3, tfeat);
  const TI Bti = tile_info(2*fb + 1, f0, f1, f2, f3, tfeat);

  nfloat4 ra[4], rb[4];
  tile_load(Ati, t, ra);
  tile_lds(smem, Ati, t, ra);
  __syncthreads();
  tile_load(Bti, t, rb);          // B loads in flight during A's store
  tile_store(smem, Ati, t);       // LDS reads + NT global stores of A
  __syncthreads();                // all reads of buf done before overwrite
  tile_lds(smem, Bti, t, rb);     // waits on B loads
  __syncthreads();
  tile_store(smem, Bti, t);
}

// ------- fused: softmax + projection + branchless compacted gather ----
// grid (NBA, SPLIT); CL=true: ALL levels channel-last from tfeat (coalesced
// 1KB taps). CL=false fallback: direct channel-first reads.
template<bool CL>
__global__ __launch_bounds__(256) void k_sample_h(
    const float* __restrict__ anchor, const float* __restrict__ proj,
    const float* __restrict__ wh, const float* __restrict__ wraw,
    const float* __restrict__ tfeat,
    const float* __restrict__ f0, const float* __restrict__ f1,
    const float* __restrict__ f2, const float* __restrict__ f3,
    float* __restrict__ fused)
{
  __shared__ float wsh[NJ];              // [g][e] layout (conflict-free)
  __shared__ float gridsh[NCAM][NP][2];
  __shared__ const float* cptr[EHALF][4]; // 4 pre-clamped tap pointers (ch 0)
  __shared__ float4 cwt[EHALF];           // validity-masked bilinear weights
  __shared__ int2   cmeta[EHALF];         // x=chstep, y=entry idx
  __shared__ int wcnt[4];

  const int ba   = blockIdx.x;
  const int half = blockIdx.y;
  const int b    = ba / A;
  const int t    = threadIdx.x;

  for (int j = t; j < NJ; j += 256)
    wsh[(j & 7) * NE + (j >> 3)] = wraw[(size_t)ba*NJ + j];

  if (t < NCAM*NP) {
    const int c = t / NP, p = t % NP;
    const float* an = anchor + (size_t)ba * 8;
    const float sx = expf(an[3]), sy = expf(an[4]), sz = expf(an[5]);
    const float sn = an[6], cs = an[7];
    const float kx = FIXS[p][0]*sx, ky = FIXS[p][1]*sy, kz = FIXS[p][2]*sz;
    const float px = cs*kx - sn*ky + an[0];
    const float py = sn*kx + cs*ky + an[1];
    const float pz = kz + an[2];
    const float* P = proj + ((size_t)(b*NCAM + c))*16;
    const float X = P[0]*px + P[1]*py + P[2]*pz  + P[3];
    const float Y = P[4]*px + P[5]*py + P[6]*pz  + P[7];
    const float Z = P[8]*px + P[9]*py + P[10]*pz + P[11];
    const float zc  = fmaxf(Z, 1e-5f);
    const float whx = fmaxf(wh[(b*NCAM+c)*2+0], 1e-5f);
    const float why = fmaxf(wh[(b*NCAM+c)*2+1], 1e-5f);
    gridsh[c][p][0] = (X/zc/whx)*2.f - 1.f;
    gridsh[c][p][1] = (Y/zc/why)*2.f - 1.f;
  }
  __syncthreads();

  // entries for this block: e = half*EHALF + (t if t < EHALF)
  bool valid = false;
  int chstep = 0;
  float4 w4 = make_float4(0.f,0.f,0.f,0.f);
  const float *p00=nullptr, *p10=nullptr, *p01=nullptr, *p11=nullptr;
  const int e = half * EHALF + t;
  if (t < EHALF) {
    const int c = e / (NL*NP); const int r = e % (NL*NP);
    const int l = r / NP, p = r % NP;
    const int Wl = cW[l], Hl = cH[l], HWl = cHW[l];
    const float gx = (gridsh[c][p][0] + 1.f) * (Wl * 0.5f) - 0.5f;
    const float gy = (gridsh[c][p][1] + 1.f) * (Hl * 0.5f) - 0.5f;
    const float x0f = floorf(gx), y0f = floorf(gy);
    const bool vx0 = (x0f >=  0.f) & (x0f <= (float)(Wl-1));
    const bool vx1 = (x0f >= -1.f) & (x0f <= (float)(Wl-2));
    const bool vy0 = (y0f >=  0.f) & (y0f <= (float)(Hl-1));
    const bool vy1 = (y0f >= -1.f) & (y0f <= (float)(Hl-2));
    if (vx0|vx1|vy0|vy1) {
      const float wx1 = gx - x0f, wy1 = gy - y0f;
      // clamp both tap coords into the image; invalid taps get weight 0
      const int x0 = (int)fmaxf(fminf(x0f,        (float)(Wl-1)), 0.f);
      const int x1 = (int)fmaxf(fminf(x0f + 1.f,  (float)(Wl-1)), 0.f);
      const int y0 = (int)fmaxf(fminf(y0f,        (float)(Hl-1)), 0.f);
      const int y1 = (int)fmaxf(fminf(y0f + 1.f,  (float)(Hl-1)), 0.f);
      w4 = make_float4((1.f-wx1)*(1.f-wy1)*(vx0&&vy0),
                       wx1*(1.f-wy1)*(vx1&&vy0),
                       (1.f-wx1)*wy1*(vx0&&vy1),
                       wx1*wy1*(vx1&&vy1));
      if (w4.x != 0.f || w4.y != 0.f || w4.z != 0.f || w4.w != 0.f) {
        const float* base;
        int estep;  // element stride for one pixel step
        if (CL) {
          base = tfeat + cLOFF[l] + (size_t)(b*NCAM + c) * HWl * ED;
          estep = ED; chstep = 1;
        } else {
          const float* fp = (l==0)?f0:(l==1)?f1:(l==2)?f2:f3;
          base = fp + (size_t)(b*NCAM + c) * ED * HWl;
          estep = 1; chstep = HWl;
        }
        p00 = base + (size_t)(y0*Wl + x0) * estep;
        p10 = base + (size_t)(y0*Wl + x1) * estep;
        p01 = base + (size_t)(y1*Wl + x0) * estep;
        p11 = base + (size_t)(y1*Wl + x1) * estep;
        valid = true;
      }
    }
  }

  const unsigned long long mask = __ballot(valid);
  const int lane = t & 63, wv = t >> 6;
  if (lane == 0) wcnt[wv] = __popcll(mask);
  __syncthreads();
  int off = 0, nv = 0;
#pragma unroll
  for (int i = 0; i < 4; ++i) { if (i < wv) off += wcnt[i]; nv += wcnt[i]; }
  if (valid) {
    const int pos = off + __popcll(mask & ((1ull << lane) - 1ull));
    cptr[pos][0] = p00; cptr[pos][1] = p10; cptr[pos][2] = p01; cptr[pos][3] = p11;
    cwt[pos]   = w4;
    cmeta[pos] = make_int2(chstep, e);
  }

  // group softmax over ALL entries (needed for correct normalization)
  {
    const int g = t >> 5, ln = t & 31;
    float* wg = wsh + g * NE;
    float m = -3.4e38f;
    for (int i = ln; i < NE; i += 32) m = fmaxf(m, wg[i]);
#pragma unroll
    for (int mk = 16; mk >= 1; mk >>= 1) m = fmaxf(m, __shfl_xor(m, mk));
    float s = 0.f;
    for (int i = ln; i < NE; i += 32) {
      const float ev = expf(wg[i] - m);
      wg[i] = ev;
      s += ev;
    }
#pragma unroll
    for (int mk = 16; mk >= 1; mk >>= 1) s += __shfl_xor(s, mk);
    const float inv = 1.f / s;
    for (int i = ln; i < NE; i += 32) wg[i] *= inv;
  }
  __syncthreads();

  float acc = 0.f;
  const int g = t >> 5;
#pragma unroll 4
  for (int i = 0; i < nv; ++i) {
    const int2 m = cmeta[i];
    const size_t toff = (size_t)t * m.x;
    const float4 w = cwt[i];
    const float aw = wsh[g*NE + m.y];
    const float v00 = cptr[i][0][toff];
    const float v10 = cptr[i][1][toff];
    const float v01 = cptr[i][2][toff];
    const float v11 = cptr[i][3][toff];
    acc += aw * (w.x*v00 + w.y*v10 + w.z*v01 + w.w*v11);
  }
  fused[((size_t)half * NBA + ba) * ED + t] = acc;
}

// ---------------- out = (fused0+fused1) @ w_out^T + b_out ----------------
__global__ __launch_bounds__(256) void k_out(const float* __restrict__ fused,
    const float* __restrict__ w_out, const float* __restrict__ b_out,
    float* __restrict__ out)
{
  __shared__ float fsh[8][ED];
  const int a0 = blockIdx.x * 8;
  const int t = threadIdx.x;
#pragma unroll
  for (int k = 0; k < 8; ++k)
    fsh[k][t] = fused[(size_t)(a0+k)*ED + t]
              + fused[(size_t)NBA*ED + (size_t)(a0+k)*ED + t];
  __syncthreads();
  float acc[8] = {0.f,0.f,0.f,0.f,0.f,0.f,0.f,0.f};
  for (int i = 0; i < ED; i += 4) {
    const float4 w4 = *(const float4*)&w_out[(size_t)t*ED + i];
#pragma unroll
    for (int k = 0; k < 8; ++k) {
      const float4 fv = *(const float4*)&fsh[k][i];
      acc[k] += w4.x*fv.x + w4.y*fv.y + w4.z*fv.z + w4.w*fv.w;
    }
  }
  const float bo = b_out[t];
#pragma unroll
  for (int k = 0; k < 8; ++k) out[(size_t)(a0+k)*ED + t] = acc[k] + bo;
}

extern "C" void kernel_launch(void* const* d_in, const int* in_sizes, int n_in,
                              void* d_out, int out_size, void* d_ws, size_t ws_size,
                              hipStream_t stream) {
  const float* inst   = (const float*)d_in[0];
  const float* anchor = (const float*)d_in[1];
  const float* emb    = (const float*)d_in[2];
  const float* f0 = (const float*)d_in[3];
  const float* f1 = (const float*)d_in[4];
  const float* f2 = (const float*)d_in[5];
  const float* f3 = (const float*)d_in[6];
  const float* proj  = (const float*)d_in[7];
  const float* wh    = (const float*)d_in[8];
  const float* w_fc  = (const float*)d_in[9];
  const float* b_fc  = (const float*)d_in[10];
  const float* w_out = (const float*)d_in[11];
  const float* b_out = (const float*)d_in[12];
  float* out = (float*)d_out;
  float* ws  = (float*)d_ws;

  const size_t TFEAT = 45957120ULL;   // ALL levels channel-last, floats
  const size_t WRAW  = (size_t)NBA * NJ;
  const size_t FUSED = (size_t)SPLIT * NBA * ED;
  const bool tr = ws_size >= (TFEAT + WRAW + FUSED) * sizeof(float);

  float* tfeat  = ws;
  float* wraw   = tr ? (ws + TFEAT) : ws;
  float* fusedp = wraw + WRAW;

  // merged: FC (1575 blocks, first) + 2-tile single-buffer transpose (5610)
  k_prep<<<NFCB + (tr ? NTRB2 : 0), 256, 0, stream>>>(f0, f1, f2, f3,
      inst, emb, w_fc, b_fc, tfeat, wraw);

  if (tr)
    k_sample_h<true><<<dim3(NBA, SPLIT), 256, 0, stream>>>(anchor, proj, wh,
        wraw, tfeat, f0, f1, f2, f3, fusedp);
  else
    k_sample_h<false><<<dim3(NBA, SPLIT), 256, 0, stream>>>(anchor, proj, wh,
        wraw, tfeat, f0, f1, f2, f3, fusedp);

  k_out<<<NBA / 8, 256, 0, stream>>>(fusedp, w_out, b_out, out);
}